// Round 19
// baseline (541.519 us; speedup 1.0000x reference)
//
#include <hip/hip_runtime.h>

#define N_NODES 100000
#define N_EDGES 800000
// IN=128, HID=256, OUT=128
#define SCAN_CHUNK 1024
#define SCAN_NB ((N_NODES + SCAN_CHUNK - 1) / SCAN_CHUNK)   // 98

typedef __attribute__((ext_vector_type(8))) _Float16 f16x8;
typedef __attribute__((ext_vector_type(4))) _Float16 f16x4;
typedef __attribute__((ext_vector_type(4))) float f32x4;

// ---------------- degree count (int atomics) ----------------
__global__ void count_int_k(const int* __restrict__ dst, int* __restrict__ cnt, int E) {
    int i = blockIdx.x * blockDim.x + threadIdx.x;
    if (i < E) atomicAdd(&cnt[dst[i]], 1);
}

// ---------------- scan pass 1 ----------------
__global__ __launch_bounds__(256) void scan1_k(const int* __restrict__ cnt,
                                               int* __restrict__ offs,
                                               int* __restrict__ bsums, int N) {
    __shared__ int s[256];
    int t = threadIdx.x;
    int base = blockIdx.x * SCAN_CHUNK + t * 4;
    int v0 = (base + 0 < N) ? cnt[base + 0] : 0;
    int v1 = (base + 1 < N) ? cnt[base + 1] : 0;
    int v2 = (base + 2 < N) ? cnt[base + 2] : 0;
    int v3 = (base + 3 < N) ? cnt[base + 3] : 0;
    int tsum = v0 + v1 + v2 + v3;
    s[t] = tsum;
    __syncthreads();
    for (int off = 1; off < 256; off <<= 1) {
        int val = (t >= off) ? s[t - off] : 0;
        __syncthreads();
        s[t] += val;
        __syncthreads();
    }
    int excl = s[t] - tsum;
    if (base + 0 < N) offs[base + 0] = excl;
    if (base + 1 < N) offs[base + 1] = excl + v0;
    if (base + 2 < N) offs[base + 2] = excl + v0 + v1;
    if (base + 3 < N) offs[base + 3] = excl + v0 + v1 + v2;
    if (t == 255) bsums[blockIdx.x] = s[255];
}

// ---------------- scan pass 2 ----------------
__global__ __launch_bounds__(256) void scan2_k(const int* __restrict__ bsums,
                                               int* __restrict__ boffs, int nb) {
    __shared__ int s[256];
    int t = threadIdx.x;
    int v = (t < nb) ? bsums[t] : 0;
    s[t] = v;
    __syncthreads();
    for (int off = 1; off < 256; off <<= 1) {
        int val = (t >= off) ? s[t - off] : 0;
        __syncthreads();
        s[t] += val;
        __syncthreads();
    }
    if (t < nb) boffs[t] = s[t] - v;
}

// ---------------- scan pass 3 ----------------
__global__ void scan3_k(int* __restrict__ offs, int* __restrict__ cursor,
                        const int* __restrict__ boffs, int N, int E) {
    int i = blockIdx.x * blockDim.x + threadIdx.x;
    if (i < N) {
        int v = offs[i] + boffs[i >> 10];
        offs[i] = v;
        cursor[i] = v;
    }
    if (i == 0) offs[N] = E;
}

// ---------------- bucket fill ----------------
__global__ void fill_k(const int* __restrict__ src, const int* __restrict__ dst,
                       int* __restrict__ cursor, int* __restrict__ perm, int E) {
    int e = blockIdx.x * blockDim.x + threadIdx.x;
    if (e < E) {
        int d = dst[e];
        int slot = atomicAdd(&cursor[d], 1);
        perm[slot] = src[e];
    }
}

// ---------------- bulk f32 -> f16 conversion (8 floats/thread) ----------------
__global__ __launch_bounds__(256) void cvt_f16_k(const float* __restrict__ in,
                                                 _Float16* __restrict__ outp, int n8) {
    int i = blockIdx.x * blockDim.x + threadIdx.x;
    if (i >= n8) return;
    const float4* p = (const float4*)in + (long long)i * 2;
    float4 v0 = p[0], v1 = p[1];
    f16x8 h;
    h[0] = (_Float16)v0.x; h[1] = (_Float16)v0.y;
    h[2] = (_Float16)v0.z; h[3] = (_Float16)v0.w;
    h[4] = (_Float16)v1.x; h[5] = (_Float16)v1.y;
    h[6] = (_Float16)v1.z; h[7] = (_Float16)v1.w;
    *(f16x8*)&outp[(long long)i * 8] = h;
}

// ---------------- gather-mean over f16 rows (f16x4/thread) -> f16 ----------------
__global__ __launch_bounds__(256) void aggmean_k(const _Float16* __restrict__ feat16,
                                                 const int* __restrict__ perm,
                                                 const int* __restrict__ offs,
                                                 _Float16* __restrict__ m16, int N) {
    int tid = threadIdx.x;
    int node = blockIdx.x * 8 + (tid >> 5);
    int q = tid & 31;                       // channels q*4..q*4+3
    if (node >= N) return;
    int beg = offs[node], end = offs[node + 1];
    float ax = 0, ay = 0, az = 0, aw = 0;
    float bx = 0, by = 0, bz = 0, bw = 0;
    int i = beg;
    for (; i + 1 < end; i += 2) {
        f16x4 v0 = *(const f16x4*)&feat16[(long long)perm[i] * 128 + q * 4];
        f16x4 v1 = *(const f16x4*)&feat16[(long long)perm[i + 1] * 128 + q * 4];
        ax += (float)v0[0]; ay += (float)v0[1]; az += (float)v0[2]; aw += (float)v0[3];
        bx += (float)v1[0]; by += (float)v1[1]; bz += (float)v1[2]; bw += (float)v1[3];
    }
    if (i < end) {
        f16x4 v0 = *(const f16x4*)&feat16[(long long)perm[i] * 128 + q * 4];
        ax += (float)v0[0]; ay += (float)v0[1]; az += (float)v0[2]; aw += (float)v0[3];
    }
    float rc = 1.0f / fmaxf((float)(end - beg), 1.0f);
    f16x4 v;
    v[0] = (_Float16)((ax + bx) * rc);
    v[1] = (_Float16)((ay + by) * rc);
    v[2] = (_Float16)((az + bz) * rc);
    v[3] = (_Float16)((aw + bw) * rc);
    *(f16x4*)&m16[(long long)node * 128 + q * 4] = v;
}

// ---------------- layer-2 agg fused epilogue: out = mean(g16) + r2(f16) + b2l ----------------
__global__ __launch_bounds__(256) void aggout_k(const _Float16* __restrict__ g16,
                                                const int* __restrict__ perm,
                                                const int* __restrict__ offs,
                                                const _Float16* __restrict__ r2h,
                                                const float* __restrict__ b2l,
                                                float* __restrict__ out, int N) {
    int tid = threadIdx.x;
    int node = blockIdx.x * 8 + (tid >> 5);
    int q = tid & 31;
    if (node >= N) return;
    int beg = offs[node], end = offs[node + 1];
    float ax = 0, ay = 0, az = 0, aw = 0;
    float bx = 0, by = 0, bz = 0, bw = 0;
    int i = beg;
    for (; i + 1 < end; i += 2) {
        f16x4 v0 = *(const f16x4*)&g16[(long long)perm[i] * 128 + q * 4];
        f16x4 v1 = *(const f16x4*)&g16[(long long)perm[i + 1] * 128 + q * 4];
        ax += (float)v0[0]; ay += (float)v0[1]; az += (float)v0[2]; aw += (float)v0[3];
        bx += (float)v1[0]; by += (float)v1[1]; bz += (float)v1[2]; bw += (float)v1[3];
    }
    if (i < end) {
        f16x4 v0 = *(const f16x4*)&g16[(long long)perm[i] * 128 + q * 4];
        ax += (float)v0[0]; ay += (float)v0[1]; az += (float)v0[2]; aw += (float)v0[3];
    }
    float rc = 1.0f / fmaxf((float)(end - beg), 1.0f);
    f16x4 rv = *(const f16x4*)&r2h[(long long)node * 128 + q * 4];
    float4 bv = ((const float4*)b2l)[q];
    float4 o;
    o.x = (ax + bx) * rc + (float)rv[0] + bv.x;
    o.y = (ay + by) * rc + (float)rv[1] + bv.y;
    o.z = (az + bz) * rc + (float)rv[2] + bv.z;
    o.w = (aw + bw) * rc + (float)rv[3] + bv.w;
    ((float4*)out)[(long long)node * 32 + q] = o;
}

// ---------------- async global->LDS, 16B/lane ----------------
__device__ inline void gload16(const void* g, void* l) {
    __builtin_amdgcn_global_load_lds(
        (const __attribute__((address_space(1))) unsigned int*)g,
        (__attribute__((address_space(3))) unsigned int*)l,
        16, 0, 0);
}

// ================= fp16 MFMA GEMM, 256x256 tile, BK=64, 4 stages ==========
// C = A @ B^T in fp16 (fp32 accumulate). 391 blocks, 512 threads = 8 waves
// (4 row-quarters wm x 2 col-halves wn); per wave 64 rows x 128 cols =
// acc[4][8] 16x16 frags (128 VGPR). K=256 in 4 stages of BK=64.
// Staging model: B (full 256-col weight panel) staged once per 256 A-rows
// (half the per-byte cost of BM=128). LDS = A 32 KiB + B 32 KiB = 64 KiB
// -> 2 blocks/CU. Swizzle: chunk c of row r at slot c^(r&7); DMA
// pre-swizzles the per-lane source chunk (k8s), one array per instruction.
// LAYER 1: A k-halves = m16/x16 (stride 128), B k-halves = W1l/W1r (128),
//   epilogue relu+bias -> h f16 (stride 256) via OH.
// LAYER 2: A = h16 (stride 256), B row<128 -> W2l else W2r (stride 256),
//   outputs g f16 (OH, cols 0..127) | r2 f16 (O1h, cols 128..255).
template <int LAYER>
__global__ __launch_bounds__(512, 4) void gemm_mfma_k(
        const _Float16* __restrict__ Ap0, const _Float16* __restrict__ Ap1,
        const _Float16* __restrict__ Bp0, const _Float16* __restrict__ Bp1,
        const float* __restrict__ bias,
        _Float16* __restrict__ O1h,
        _Float16* __restrict__ OH, int N) {
    constexpr int RSA = (LAYER == 1) ? 128 : 256;   // A row stride (halfs)
    __shared__ _Float16 As[256 * 64];   // 32 KiB
    __shared__ _Float16 Bs[256 * 64];   // 32 KiB

    const int m0 = blockIdx.x * 256;
    const int tid = threadIdx.x;
    const int lane = tid & 63;
    const int wid = tid >> 6;           // 0..7
    const int wm = wid >> 1, wn = wid & 1;
    const int lr = lane & 15, lg = lane >> 4;

    // DMA lane geometry: 8 rows x 8 slots x 16 B = 1 KB per issue
    const int r8 = lane >> 3;
    const int scs = lane & 7;
    const int k8s = scs ^ r8;          // pre-swizzled source chunk within 128 B slice

    f32x4 acc[4][8];
#pragma unroll
    for (int i = 0; i < 4; i++)
#pragma unroll
        for (int j = 0; j < 8; j++) acc[i][j] = (f32x4)0.0f;

#pragma unroll
    for (int kt = 0; kt < 4; ++kt) {
        __syncthreads();    // previous stage's readers done
        // ---- STAGE kt: A 32 segs (4/wave), B 32 segs (4/wave) ----
        {
            const _Float16* Asrc;
            int aoffk;
            if constexpr (LAYER == 1) { Asrc = (kt < 2) ? Ap0 : Ap1; aoffk = (kt & 1) * 64; }
            else                      { Asrc = Ap0;                  aoffk = kt * 64; }
#pragma unroll
            for (int it = 0; it < 4; ++it) {
                int seg = wid * 4 + it;          // 0..31
                int row = seg * 8 + r8;          // 0..255
                int gn = m0 + row;
                if (gn < N)
                    gload16(Asrc + (long long)gn * RSA + aoffk + k8s * 8, &As[seg * 512]);
            }
#pragma unroll
            for (int it = 0; it < 4; ++it) {
                int seg = wid * 4 + it;          // 0..31
                int row = seg * 8 + r8;          // 0..255 (output col)
                const _Float16* Bsrc;
                long long boff;
                if constexpr (LAYER == 1) {
                    Bsrc = (kt < 2) ? Bp0 : Bp1;             // W1l / W1r, rows 0..255
                    boff = (long long)row * 128 + (kt & 1) * 64;
                } else {
                    Bsrc = (row < 128) ? Bp0 : Bp1;          // W2l / W2r
                    boff = (long long)(row & 127) * 256 + kt * 64;
                }
                gload16(Bsrc + boff + k8s * 8, &Bs[seg * 512]);
            }
        }
        __syncthreads();    // drain DMA: stage kt ready

        // ---- COMPUTE: 2 k-steps of 32 ----
#pragma unroll
        for (int ks = 0; ks < 2; ++ks) {
            const int c = ks * 4 + lg;           // k-chunk 0..7
            f16x8 bf[8];
#pragma unroll
            for (int fc = 0; fc < 8; ++fc) {
                int c_ = wn * 128 + fc * 16 + lr;            // 0..255
                bf[fc] = *(const f16x8*)&Bs[c_ * 64 + (c ^ (c_ & 7)) * 8];
            }
#pragma unroll
            for (int fr = 0; fr < 4; ++fr) {
                int r_ = wm * 64 + fr * 16 + lr;             // 0..255
                f16x8 af = *(const f16x8*)&As[r_ * 64 + (c ^ (r_ & 7)) * 8];
#pragma unroll
                for (int fc = 0; fc < 8; ++fc)
                    acc[fr][fc] = __builtin_amdgcn_mfma_f32_16x16x32_f16(af, bf[fc], acc[fr][fc], 0, 0, 0);
            }
        }
    }

    // ---- epilogue: C/D map col=lane&15, row=(lane>>4)*4+reg ----
    if constexpr (LAYER == 1) {
#pragma unroll
        for (int fc = 0; fc < 8; ++fc) {
            int col = wn * 128 + fc * 16 + lr;      // 0..255
            float bv = bias[col];
#pragma unroll
            for (int fr = 0; fr < 4; ++fr) {
#pragma unroll
                for (int j = 0; j < 4; ++j) {
                    int row = m0 + wm * 64 + fr * 16 + lg * 4 + j;
                    if (row < N)
                        OH[(long long)row * 256 + col] =
                            (_Float16)fmaxf(acc[fr][fc][j] + bv, 0.0f);
                }
            }
        }
    } else {
#pragma unroll
        for (int fc = 0; fc < 8; ++fc) {
            int col = wn * 128 + fc * 16 + lr;      // 0..255
            _Float16* dp = (col < 128) ? OH : O1h;  // g | r2 (uniform per wn)
            int dcol = col & 127;
#pragma unroll
            for (int fr = 0; fr < 4; ++fr) {
#pragma unroll
                for (int j = 0; j < 4; ++j) {
                    int row = m0 + wm * 64 + fr * 16 + lg * 4 + j;
                    if (row < N)
                        dp[(long long)row * 128 + dcol] = (_Float16)acc[fr][fc][j];
                }
            }
        }
    }
}

extern "C" void kernel_launch(void* const* d_in, const int* in_sizes, int n_in,
                              void* d_out, int out_size, void* d_ws, size_t ws_size,
                              hipStream_t stream) {
    const float* x   = (const float*)d_in[0];
    const int*   ei  = (const int*)d_in[1];     // [2, E]
    const float* W1l = (const float*)d_in[2];
    const float* b1l = (const float*)d_in[3];
    const float* W1r = (const float*)d_in[4];
    const float* W2l = (const float*)d_in[5];
    const float* b2l = (const float*)d_in[6];
    const float* W2r = (const float*)d_in[7];
    float* out = (float*)d_out;

    const int N = N_NODES, E = N_EDGES;
    const int* srcI = ei;
    const int* dstI = ei + E;

    char* ws = (char*)d_ws;
    size_t off = 0;
    auto alloc = [&](size_t bytes) {
        size_t o = off;
        off += (bytes + 511) & ~(size_t)511;
        return o;
    };
    size_t off_cnt   = alloc((size_t)N * 4);
    size_t off_offs  = alloc((size_t)(N + 1) * 4);
    size_t off_cur   = alloc((size_t)N * 4);
    size_t off_bsum  = alloc((size_t)SCAN_NB * 4);
    size_t off_boff  = alloc((size_t)SCAN_NB * 4);
    size_t off_perm  = alloc((size_t)E * 4);
    size_t off_x16   = alloc((size_t)N * 128 * 2);     // x f16
    size_t off_m16   = alloc((size_t)N * 128 * 2);     // mean f16
    size_t off_h16   = alloc((size_t)N * 256 * 2);     // h f16
    size_t off_g16   = alloc((size_t)N * 128 * 2);     // g f16
    size_t off_r2    = alloc((size_t)N * 128 * 2);     // r2 f16
    size_t off_w     = alloc((size_t)4 * 32768 * 2);   // 4 f16 weights
    int*      cntI = (int*)(ws + off_cnt);
    int*      offs = (int*)(ws + off_offs);
    int*      cur  = (int*)(ws + off_cur);
    int*      bsum = (int*)(ws + off_bsum);
    int*      boff = (int*)(ws + off_boff);
    int*      perm = (int*)(ws + off_perm);
    _Float16* x16  = (_Float16*)(ws + off_x16);
    _Float16* m16  = (_Float16*)(ws + off_m16);
    _Float16* h16  = (_Float16*)(ws + off_h16);
    _Float16* g16  = (_Float16*)(ws + off_g16);
    _Float16* r2h  = (_Float16*)(ws + off_r2);
    _Float16* wbuf = (_Float16*)(ws + off_w);
    const int WSZ = 32768;                             // 256*128 elems
    _Float16* w1l16 = wbuf;            _Float16* w1r16 = wbuf + WSZ;
    _Float16* w2l16 = wbuf + 2 * WSZ;  _Float16* w2r16 = wbuf + 3 * WSZ;

    // ---- CSR build ----
    (void)hipMemsetAsync(cntI, 0, (size_t)N * 4, stream);
    count_int_k<<<(E + 255) / 256, 256, 0, stream>>>(dstI, cntI, E);
    scan1_k<<<SCAN_NB, 256, 0, stream>>>(cntI, offs, bsum, N);
    scan2_k<<<1, 256, 0, stream>>>(bsum, boff, SCAN_NB);
    scan3_k<<<(N + 255) / 256, 256, 0, stream>>>(offs, cur, boff, N, E);
    fill_k<<<(E + 255) / 256, 256, 0, stream>>>(srcI, dstI, cur, perm, E);

    // ---- f16 conversions ----
    {
        int n8x = N * 16;                          // N*128/8
        cvt_f16_k<<<(n8x + 255) / 256, 256, 0, stream>>>(x, x16, n8x);
        int n8w = 32768 / 8;                       // 4096
        cvt_f16_k<<<(n8w + 255) / 256, 256, 0, stream>>>(W1l, w1l16, n8w);
        cvt_f16_k<<<(n8w + 255) / 256, 256, 0, stream>>>(W1r, w1r16, n8w);
        cvt_f16_k<<<(n8w + 255) / 256, 256, 0, stream>>>(W2l, w2l16, n8w);
        cvt_f16_k<<<(n8w + 255) / 256, 256, 0, stream>>>(W2r, w2r16, n8w);
    }

    // ---- layer 1 ----
    aggmean_k<<<(N + 7) / 8, 256, 0, stream>>>(x16, perm, offs, m16, N);
    {
        int nblk = (N + 255) / 256;   // 391
        gemm_mfma_k<1><<<nblk, 512, 0, stream>>>(m16, x16, w1l16, w1r16,
                                                 b1l, nullptr, h16, N);
    }

    // ---- layer 2 ----
    {
        int nblk = (N + 255) / 256;
        gemm_mfma_k<2><<<nblk, 512, 0, stream>>>(h16, h16, w2l16, w2r16,
                                                 nullptr, r2h, g16, N);
    }
    aggout_k<<<(N + 7) / 8, 256, 0, stream>>>(g16, perm, offs, r2h, b2l, out, N);
}

// Round 20
// 295.433 us; speedup vs baseline: 1.8330x; 1.8330x over previous
//
#include <hip/hip_runtime.h>

#define N_NODES 100000
#define N_EDGES 800000
// IN=128, HID=256, OUT=128
#define SCAN_CHUNK 1024
#define SCAN_NB ((N_NODES + SCAN_CHUNK - 1) / SCAN_CHUNK)   // 98

typedef __attribute__((ext_vector_type(8))) _Float16 f16x8;
typedef __attribute__((ext_vector_type(4))) _Float16 f16x4;
typedef __attribute__((ext_vector_type(4))) float f32x4;

// ---------------- degree count (int atomics) ----------------
__global__ void count_int_k(const int* __restrict__ dst, int* __restrict__ cnt, int E) {
    int i = blockIdx.x * blockDim.x + threadIdx.x;
    if (i < E) atomicAdd(&cnt[dst[i]], 1);
}

// ---------------- scan pass 1 ----------------
__global__ __launch_bounds__(256) void scan1_k(const int* __restrict__ cnt,
                                               int* __restrict__ offs,
                                               int* __restrict__ bsums, int N) {
    __shared__ int s[256];
    int t = threadIdx.x;
    int base = blockIdx.x * SCAN_CHUNK + t * 4;
    int v0 = (base + 0 < N) ? cnt[base + 0] : 0;
    int v1 = (base + 1 < N) ? cnt[base + 1] : 0;
    int v2 = (base + 2 < N) ? cnt[base + 2] : 0;
    int v3 = (base + 3 < N) ? cnt[base + 3] : 0;
    int tsum = v0 + v1 + v2 + v3;
    s[t] = tsum;
    __syncthreads();
    for (int off = 1; off < 256; off <<= 1) {
        int val = (t >= off) ? s[t - off] : 0;
        __syncthreads();
        s[t] += val;
        __syncthreads();
    }
    int excl = s[t] - tsum;
    if (base + 0 < N) offs[base + 0] = excl;
    if (base + 1 < N) offs[base + 1] = excl + v0;
    if (base + 2 < N) offs[base + 2] = excl + v0 + v1;
    if (base + 3 < N) offs[base + 3] = excl + v0 + v1 + v2;
    if (t == 255) bsums[blockIdx.x] = s[255];
}

// ---------------- scan pass 2 ----------------
__global__ __launch_bounds__(256) void scan2_k(const int* __restrict__ bsums,
                                               int* __restrict__ boffs, int nb) {
    __shared__ int s[256];
    int t = threadIdx.x;
    int v = (t < nb) ? bsums[t] : 0;
    s[t] = v;
    __syncthreads();
    for (int off = 1; off < 256; off <<= 1) {
        int val = (t >= off) ? s[t - off] : 0;
        __syncthreads();
        s[t] += val;
        __syncthreads();
    }
    if (t < nb) boffs[t] = s[t] - v;
}

// ---------------- scan pass 3 ----------------
__global__ void scan3_k(int* __restrict__ offs, int* __restrict__ cursor,
                        const int* __restrict__ boffs, int N, int E) {
    int i = blockIdx.x * blockDim.x + threadIdx.x;
    if (i < N) {
        int v = offs[i] + boffs[i >> 10];
        offs[i] = v;
        cursor[i] = v;
    }
    if (i == 0) offs[N] = E;
}

// ---------------- bucket fill ----------------
__global__ void fill_k(const int* __restrict__ src, const int* __restrict__ dst,
                       int* __restrict__ cursor, int* __restrict__ perm, int E) {
    int e = blockIdx.x * blockDim.x + threadIdx.x;
    if (e < E) {
        int d = dst[e];
        int slot = atomicAdd(&cursor[d], 1);
        perm[slot] = src[e];
    }
}

// ---------------- bulk f32 -> f16 conversion (8 floats/thread) ----------------
__global__ __launch_bounds__(256) void cvt_f16_k(const float* __restrict__ in,
                                                 _Float16* __restrict__ outp, int n8) {
    int i = blockIdx.x * blockDim.x + threadIdx.x;
    if (i >= n8) return;
    const float4* p = (const float4*)in + (long long)i * 2;
    float4 v0 = p[0], v1 = p[1];
    f16x8 h;
    h[0] = (_Float16)v0.x; h[1] = (_Float16)v0.y;
    h[2] = (_Float16)v0.z; h[3] = (_Float16)v0.w;
    h[4] = (_Float16)v1.x; h[5] = (_Float16)v1.y;
    h[6] = (_Float16)v1.z; h[7] = (_Float16)v1.w;
    *(f16x8*)&outp[(long long)i * 8] = h;
}

// ---------------- gather-mean over f16 rows (f16x4/thread) -> f16 ----------------
__global__ __launch_bounds__(256) void aggmean_k(const _Float16* __restrict__ feat16,
                                                 const int* __restrict__ perm,
                                                 const int* __restrict__ offs,
                                                 _Float16* __restrict__ m16, int N) {
    int tid = threadIdx.x;
    int node = blockIdx.x * 8 + (tid >> 5);
    int q = tid & 31;                       // channels q*4..q*4+3
    if (node >= N) return;
    int beg = offs[node], end = offs[node + 1];
    float ax = 0, ay = 0, az = 0, aw = 0;
    float bx = 0, by = 0, bz = 0, bw = 0;
    int i = beg;
    for (; i + 1 < end; i += 2) {
        f16x4 v0 = *(const f16x4*)&feat16[(long long)perm[i] * 128 + q * 4];
        f16x4 v1 = *(const f16x4*)&feat16[(long long)perm[i + 1] * 128 + q * 4];
        ax += (float)v0[0]; ay += (float)v0[1]; az += (float)v0[2]; aw += (float)v0[3];
        bx += (float)v1[0]; by += (float)v1[1]; bz += (float)v1[2]; bw += (float)v1[3];
    }
    if (i < end) {
        f16x4 v0 = *(const f16x4*)&feat16[(long long)perm[i] * 128 + q * 4];
        ax += (float)v0[0]; ay += (float)v0[1]; az += (float)v0[2]; aw += (float)v0[3];
    }
    float rc = 1.0f / fmaxf((float)(end - beg), 1.0f);
    f16x4 v;
    v[0] = (_Float16)((ax + bx) * rc);
    v[1] = (_Float16)((ay + by) * rc);
    v[2] = (_Float16)((az + bz) * rc);
    v[3] = (_Float16)((aw + bw) * rc);
    *(f16x4*)&m16[(long long)node * 128 + q * 4] = v;
}

// ---------------- layer-2 agg fused epilogue: out = mean(g16) + r2(f16) + b2l ----------------
__global__ __launch_bounds__(256) void aggout_k(const _Float16* __restrict__ g16,
                                                const int* __restrict__ perm,
                                                const int* __restrict__ offs,
                                                const _Float16* __restrict__ r2h,
                                                const float* __restrict__ b2l,
                                                float* __restrict__ out, int N) {
    int tid = threadIdx.x;
    int node = blockIdx.x * 8 + (tid >> 5);
    int q = tid & 31;
    if (node >= N) return;
    int beg = offs[node], end = offs[node + 1];
    float ax = 0, ay = 0, az = 0, aw = 0;
    float bx = 0, by = 0, bz = 0, bw = 0;
    int i = beg;
    for (; i + 1 < end; i += 2) {
        f16x4 v0 = *(const f16x4*)&g16[(long long)perm[i] * 128 + q * 4];
        f16x4 v1 = *(const f16x4*)&g16[(long long)perm[i + 1] * 128 + q * 4];
        ax += (float)v0[0]; ay += (float)v0[1]; az += (float)v0[2]; aw += (float)v0[3];
        bx += (float)v1[0]; by += (float)v1[1]; bz += (float)v1[2]; bw += (float)v1[3];
    }
    if (i < end) {
        f16x4 v0 = *(const f16x4*)&g16[(long long)perm[i] * 128 + q * 4];
        ax += (float)v0[0]; ay += (float)v0[1]; az += (float)v0[2]; aw += (float)v0[3];
    }
    float rc = 1.0f / fmaxf((float)(end - beg), 1.0f);
    f16x4 rv = *(const f16x4*)&r2h[(long long)node * 128 + q * 4];
    float4 bv = ((const float4*)b2l)[q];
    float4 o;
    o.x = (ax + bx) * rc + (float)rv[0] + bv.x;
    o.y = (ay + by) * rc + (float)rv[1] + bv.y;
    o.z = (az + bz) * rc + (float)rv[2] + bv.z;
    o.w = (aw + bw) * rc + (float)rv[3] + bv.w;
    ((float4*)out)[(long long)node * 32 + q] = o;
}

// ---------------- async global->LDS, 16B/lane ----------------
__device__ inline void gload16(const void* g, void* l) {
    __builtin_amdgcn_global_load_lds(
        (const __attribute__((address_space(1))) unsigned int*)g,
        (__attribute__((address_space(3))) unsigned int*)l,
        16, 0, 0);
}

// ================= fp16 MFMA GEMM, 256x256 tile, 16 waves, BK=64, 4 stages ==========
// C = A @ B^T in fp16 (fp32 accumulate). 391 blocks, 1024 threads = 16 waves
// (4 row-quarters wm x 4 col-quarters wn); per wave 64x64 = acc[4][4]
// (64 VGPR acc/thread -- same spill-free profile as the 297us r18 kernel).
// K=256 in 4 stages of BK=64. B (full 256-col weight panel) staged once per
// 256 A-rows: staged bytes = 51(A)+51(B) = 102 MB vs r18's 151 MB.
// LDS = A 32 KiB + B 32 KiB = 64 KiB -> 1 block/CU.
// Swizzle: chunk c of row r at slot c^(r&7); DMA pre-swizzles per-lane chunk.
// LAYER 1: A k-halves = m16/x16 (stride 128), B k-halves = W1l/W1r (128),
//   epilogue relu+bias -> h f16 (stride 256) via OH.
// LAYER 2: A = h16 (stride 256), B row<128 -> W2l else W2r (stride 256),
//   outputs g f16 (OH, cols 0..127) | r2 f16 (O1h, cols 128..255).
template <int LAYER>
__global__ __launch_bounds__(1024, 4) void gemm_mfma_k(
        const _Float16* __restrict__ Ap0, const _Float16* __restrict__ Ap1,
        const _Float16* __restrict__ Bp0, const _Float16* __restrict__ Bp1,
        const float* __restrict__ bias,
        _Float16* __restrict__ O1h,
        _Float16* __restrict__ OH, int N) {
    constexpr int RSA = (LAYER == 1) ? 128 : 256;   // A row stride (halfs)
    __shared__ _Float16 As[256 * 64];   // 32 KiB
    __shared__ _Float16 Bs[256 * 64];   // 32 KiB

    const int m0 = blockIdx.x * 256;
    const int tid = threadIdx.x;
    const int lane = tid & 63;
    const int wid = tid >> 6;           // 0..15
    const int wm = wid >> 2, wn = wid & 3;
    const int lr = lane & 15, lg = lane >> 4;

    // DMA lane geometry: 8 rows x 8 slots x 16 B = 1 KB per issue
    const int r8 = lane >> 3;
    const int scs = lane & 7;
    const int k8s = scs ^ r8;          // pre-swizzled source chunk within 128 B slice

    f32x4 acc[4][4];
#pragma unroll
    for (int i = 0; i < 4; i++)
#pragma unroll
        for (int j = 0; j < 4; j++) acc[i][j] = (f32x4)0.0f;

#pragma unroll
    for (int kt = 0; kt < 4; ++kt) {
        __syncthreads();    // previous stage's readers done
        // ---- STAGE kt: A 32 segs (2/wave), B 32 segs (2/wave) ----
        {
            const _Float16* Asrc;
            int aoffk;
            if constexpr (LAYER == 1) { Asrc = (kt < 2) ? Ap0 : Ap1; aoffk = (kt & 1) * 64; }
            else                      { Asrc = Ap0;                  aoffk = kt * 64; }
#pragma unroll
            for (int it = 0; it < 2; ++it) {
                int seg = wid * 2 + it;          // 0..31
                int row = seg * 8 + r8;          // 0..255
                int gn = m0 + row;
                if (gn < N)
                    gload16(Asrc + (long long)gn * RSA + aoffk + k8s * 8, &As[seg * 512]);
            }
#pragma unroll
            for (int it = 0; it < 2; ++it) {
                int seg = wid * 2 + it;          // 0..31
                int row = seg * 8 + r8;          // 0..255 (output col)
                const _Float16* Bsrc;
                long long boff;
                if constexpr (LAYER == 1) {
                    Bsrc = (kt < 2) ? Bp0 : Bp1;             // W1l / W1r, rows 0..255
                    boff = (long long)row * 128 + (kt & 1) * 64;
                } else {
                    Bsrc = (row < 128) ? Bp0 : Bp1;          // W2l / W2r
                    boff = (long long)(row & 127) * 256 + kt * 64;
                }
                gload16(Bsrc + boff + k8s * 8, &Bs[seg * 512]);
            }
        }
        __syncthreads();    // drain DMA: stage kt ready

        // ---- COMPUTE: 2 k-steps of 32 ----
#pragma unroll
        for (int ks = 0; ks < 2; ++ks) {
            const int c = ks * 4 + lg;           // k-chunk 0..7
            f16x8 bf[4];
#pragma unroll
            for (int fc = 0; fc < 4; ++fc) {
                int c_ = wn * 64 + fc * 16 + lr;             // 0..255
                bf[fc] = *(const f16x8*)&Bs[c_ * 64 + (c ^ (c_ & 7)) * 8];
            }
#pragma unroll
            for (int fr = 0; fr < 4; ++fr) {
                int r_ = wm * 64 + fr * 16 + lr;             // 0..255
                f16x8 af = *(const f16x8*)&As[r_ * 64 + (c ^ (r_ & 7)) * 8];
#pragma unroll
                for (int fc = 0; fc < 4; ++fc)
                    acc[fr][fc] = __builtin_amdgcn_mfma_f32_16x16x32_f16(af, bf[fc], acc[fr][fc], 0, 0, 0);
            }
        }
    }

    // ---- epilogue: C/D map col=lane&15, row=(lane>>4)*4+reg ----
    if constexpr (LAYER == 1) {
#pragma unroll
        for (int fc = 0; fc < 4; ++fc) {
            int col = wn * 64 + fc * 16 + lr;       // 0..255
            float bv = bias[col];
#pragma unroll
            for (int fr = 0; fr < 4; ++fr) {
#pragma unroll
                for (int j = 0; j < 4; ++j) {
                    int row = m0 + wm * 64 + fr * 16 + lg * 4 + j;
                    if (row < N)
                        OH[(long long)row * 256 + col] =
                            (_Float16)fmaxf(acc[fr][fc][j] + bv, 0.0f);
                }
            }
        }
    } else {
#pragma unroll
        for (int fc = 0; fc < 4; ++fc) {
            int col = wn * 64 + fc * 16 + lr;       // 0..255
            _Float16* dp = (col < 128) ? OH : O1h;  // g | r2 (uniform per wn)
            int dcol = col & 127;
#pragma unroll
            for (int fr = 0; fr < 4; ++fr) {
#pragma unroll
                for (int j = 0; j < 4; ++j) {
                    int row = m0 + wm * 64 + fr * 16 + lg * 4 + j;
                    if (row < N)
                        dp[(long long)row * 128 + dcol] = (_Float16)acc[fr][fc][j];
                }
            }
        }
    }
}

extern "C" void kernel_launch(void* const* d_in, const int* in_sizes, int n_in,
                              void* d_out, int out_size, void* d_ws, size_t ws_size,
                              hipStream_t stream) {
    const float* x   = (const float*)d_in[0];
    const int*   ei  = (const int*)d_in[1];     // [2, E]
    const float* W1l = (const float*)d_in[2];
    const float* b1l = (const float*)d_in[3];
    const float* W1r = (const float*)d_in[4];
    const float* W2l = (const float*)d_in[5];
    const float* b2l = (const float*)d_in[6];
    const float* W2r = (const float*)d_in[7];
    float* out = (float*)d_out;

    const int N = N_NODES, E = N_EDGES;
    const int* srcI = ei;
    const int* dstI = ei + E;

    char* ws = (char*)d_ws;
    size_t off = 0;
    auto alloc = [&](size_t bytes) {
        size_t o = off;
        off += (bytes + 511) & ~(size_t)511;
        return o;
    };
    size_t off_cnt   = alloc((size_t)N * 4);
    size_t off_offs  = alloc((size_t)(N + 1) * 4);
    size_t off_cur   = alloc((size_t)N * 4);
    size_t off_bsum  = alloc((size_t)SCAN_NB * 4);
    size_t off_boff  = alloc((size_t)SCAN_NB * 4);
    size_t off_perm  = alloc((size_t)E * 4);
    size_t off_x16   = alloc((size_t)N * 128 * 2);     // x f16
    size_t off_m16   = alloc((size_t)N * 128 * 2);     // mean f16
    size_t off_h16   = alloc((size_t)N * 256 * 2);     // h f16
    size_t off_g16   = alloc((size_t)N * 128 * 2);     // g f16
    size_t off_r2    = alloc((size_t)N * 128 * 2);     // r2 f16
    size_t off_w     = alloc((size_t)4 * 32768 * 2);   // 4 f16 weights
    int*      cntI = (int*)(ws + off_cnt);
    int*      offs = (int*)(ws + off_offs);
    int*      cur  = (int*)(ws + off_cur);
    int*      bsum = (int*)(ws + off_bsum);
    int*      boff = (int*)(ws + off_boff);
    int*      perm = (int*)(ws + off_perm);
    _Float16* x16  = (_Float16*)(ws + off_x16);
    _Float16* m16  = (_Float16*)(ws + off_m16);
    _Float16* h16  = (_Float16*)(ws + off_h16);
    _Float16* g16  = (_Float16*)(ws + off_g16);
    _Float16* r2h  = (_Float16*)(ws + off_r2);
    _Float16* wbuf = (_Float16*)(ws + off_w);
    const int WSZ = 32768;                             // 256*128 elems
    _Float16* w1l16 = wbuf;            _Float16* w1r16 = wbuf + WSZ;
    _Float16* w2l16 = wbuf + 2 * WSZ;  _Float16* w2r16 = wbuf + 3 * WSZ;

    // ---- CSR build ----
    (void)hipMemsetAsync(cntI, 0, (size_t)N * 4, stream);
    count_int_k<<<(E + 255) / 256, 256, 0, stream>>>(dstI, cntI, E);
    scan1_k<<<SCAN_NB, 256, 0, stream>>>(cntI, offs, bsum, N);
    scan2_k<<<1, 256, 0, stream>>>(bsum, boff, SCAN_NB);
    scan3_k<<<(N + 255) / 256, 256, 0, stream>>>(offs, cur, boff, N, E);
    fill_k<<<(E + 255) / 256, 256, 0, stream>>>(srcI, dstI, cur, perm, E);

    // ---- f16 conversions ----
    {
        int n8x = N * 16;                          // N*128/8
        cvt_f16_k<<<(n8x + 255) / 256, 256, 0, stream>>>(x, x16, n8x);
        int n8w = 32768 / 8;                       // 4096
        cvt_f16_k<<<(n8w + 255) / 256, 256, 0, stream>>>(W1l, w1l16, n8w);
        cvt_f16_k<<<(n8w + 255) / 256, 256, 0, stream>>>(W1r, w1r16, n8w);
        cvt_f16_k<<<(n8w + 255) / 256, 256, 0, stream>>>(W2l, w2l16, n8w);
        cvt_f16_k<<<(n8w + 255) / 256, 256, 0, stream>>>(W2r, w2r16, n8w);
    }

    // ---- layer 1 ----
    aggmean_k<<<(N + 7) / 8, 256, 0, stream>>>(x16, perm, offs, m16, N);
    {
        int nblk = (N + 255) / 256;   // 391
        gemm_mfma_k<1><<<nblk, 1024, 0, stream>>>(m16, x16, w1l16, w1r16,
                                                  b1l, nullptr, h16, N);
    }

    // ---- layer 2 ----
    {
        int nblk = (N + 255) / 256;
        gemm_mfma_k<2><<<nblk, 1024, 0, stream>>>(h16, h16, w2l16, w2r16,
                                                  nullptr, r2h, g16, N);
    }
    aggout_k<<<(N + 7) / 8, 256, 0, stream>>>(g16, perm, offs, r2h, b2l, out, N);
}

// Round 21
// 293.593 us; speedup vs baseline: 1.8445x; 1.0063x over previous
//
#include <hip/hip_runtime.h>

#define N_NODES 100000
#define N_EDGES 800000
// IN=128, HID=256, OUT=128
#define SCAN_CHUNK 1024
#define SCAN_NB ((N_NODES + SCAN_CHUNK - 1) / SCAN_CHUNK)   // 98

typedef __attribute__((ext_vector_type(8))) _Float16 f16x8;
typedef __attribute__((ext_vector_type(4))) _Float16 f16x4;
typedef __attribute__((ext_vector_type(4))) float f32x4;

// ---------------- degree count (int atomics) ----------------
__global__ void count_int_k(const int* __restrict__ dst, int* __restrict__ cnt, int E) {
    int i = blockIdx.x * blockDim.x + threadIdx.x;
    if (i < E) atomicAdd(&cnt[dst[i]], 1);
}

// ---------------- scan pass 1 ----------------
__global__ __launch_bounds__(256) void scan1_k(const int* __restrict__ cnt,
                                               int* __restrict__ offs,
                                               int* __restrict__ bsums, int N) {
    __shared__ int s[256];
    int t = threadIdx.x;
    int base = blockIdx.x * SCAN_CHUNK + t * 4;
    int v0 = (base + 0 < N) ? cnt[base + 0] : 0;
    int v1 = (base + 1 < N) ? cnt[base + 1] : 0;
    int v2 = (base + 2 < N) ? cnt[base + 2] : 0;
    int v3 = (base + 3 < N) ? cnt[base + 3] : 0;
    int tsum = v0 + v1 + v2 + v3;
    s[t] = tsum;
    __syncthreads();
    for (int off = 1; off < 256; off <<= 1) {
        int val = (t >= off) ? s[t - off] : 0;
        __syncthreads();
        s[t] += val;
        __syncthreads();
    }
    int excl = s[t] - tsum;
    if (base + 0 < N) offs[base + 0] = excl;
    if (base + 1 < N) offs[base + 1] = excl + v0;
    if (base + 2 < N) offs[base + 2] = excl + v0 + v1;
    if (base + 3 < N) offs[base + 3] = excl + v0 + v1 + v2;
    if (t == 255) bsums[blockIdx.x] = s[255];
}

// ---------------- scan pass 2 ----------------
__global__ __launch_bounds__(256) void scan2_k(const int* __restrict__ bsums,
                                               int* __restrict__ boffs, int nb) {
    __shared__ int s[256];
    int t = threadIdx.x;
    int v = (t < nb) ? bsums[t] : 0;
    s[t] = v;
    __syncthreads();
    for (int off = 1; off < 256; off <<= 1) {
        int val = (t >= off) ? s[t - off] : 0;
        __syncthreads();
        s[t] += val;
        __syncthreads();
    }
    if (t < nb) boffs[t] = s[t] - v;
}

// ---------------- scan pass 3 ----------------
__global__ void scan3_k(int* __restrict__ offs, int* __restrict__ cursor,
                        const int* __restrict__ boffs, int N, int E) {
    int i = blockIdx.x * blockDim.x + threadIdx.x;
    if (i < N) {
        int v = offs[i] + boffs[i >> 10];
        offs[i] = v;
        cursor[i] = v;
    }
    if (i == 0) offs[N] = E;
}

// ---------------- bucket fill ----------------
__global__ void fill_k(const int* __restrict__ src, const int* __restrict__ dst,
                       int* __restrict__ cursor, int* __restrict__ perm, int E) {
    int e = blockIdx.x * blockDim.x + threadIdx.x;
    if (e < E) {
        int d = dst[e];
        int slot = atomicAdd(&cursor[d], 1);
        perm[slot] = src[e];
    }
}

// ---------------- bulk f32 -> f16 conversion (8 floats/thread) ----------------
__global__ __launch_bounds__(256) void cvt_f16_k(const float* __restrict__ in,
                                                 _Float16* __restrict__ outp, int n8) {
    int i = blockIdx.x * blockDim.x + threadIdx.x;
    if (i >= n8) return;
    const float4* p = (const float4*)in + (long long)i * 2;
    float4 v0 = p[0], v1 = p[1];
    f16x8 h;
    h[0] = (_Float16)v0.x; h[1] = (_Float16)v0.y;
    h[2] = (_Float16)v0.z; h[3] = (_Float16)v0.w;
    h[4] = (_Float16)v1.x; h[5] = (_Float16)v1.y;
    h[6] = (_Float16)v1.z; h[7] = (_Float16)v1.w;
    *(f16x8*)&outp[(long long)i * 8] = h;
}

// ---------------- gather-mean over f16 rows (f16x4/thread) -> f16 ----------------
__global__ __launch_bounds__(256) void aggmean_k(const _Float16* __restrict__ feat16,
                                                 const int* __restrict__ perm,
                                                 const int* __restrict__ offs,
                                                 _Float16* __restrict__ m16, int N) {
    int tid = threadIdx.x;
    int node = blockIdx.x * 8 + (tid >> 5);
    int q = tid & 31;                       // channels q*4..q*4+3
    if (node >= N) return;
    int beg = offs[node], end = offs[node + 1];
    float ax = 0, ay = 0, az = 0, aw = 0;
    float bx = 0, by = 0, bz = 0, bw = 0;
    int i = beg;
    for (; i + 1 < end; i += 2) {
        f16x4 v0 = *(const f16x4*)&feat16[(long long)perm[i] * 128 + q * 4];
        f16x4 v1 = *(const f16x4*)&feat16[(long long)perm[i + 1] * 128 + q * 4];
        ax += (float)v0[0]; ay += (float)v0[1]; az += (float)v0[2]; aw += (float)v0[3];
        bx += (float)v1[0]; by += (float)v1[1]; bz += (float)v1[2]; bw += (float)v1[3];
    }
    if (i < end) {
        f16x4 v0 = *(const f16x4*)&feat16[(long long)perm[i] * 128 + q * 4];
        ax += (float)v0[0]; ay += (float)v0[1]; az += (float)v0[2]; aw += (float)v0[3];
    }
    float rc = 1.0f / fmaxf((float)(end - beg), 1.0f);
    f16x4 v;
    v[0] = (_Float16)((ax + bx) * rc);
    v[1] = (_Float16)((ay + by) * rc);
    v[2] = (_Float16)((az + bz) * rc);
    v[3] = (_Float16)((aw + bw) * rc);
    *(f16x4*)&m16[(long long)node * 128 + q * 4] = v;
}

// ---------------- layer-2 agg fused epilogue: out = mean(g16) + r2(f16) + b2l ----------------
__global__ __launch_bounds__(256) void aggout_k(const _Float16* __restrict__ g16,
                                                const int* __restrict__ perm,
                                                const int* __restrict__ offs,
                                                const _Float16* __restrict__ r2h,
                                                const float* __restrict__ b2l,
                                                float* __restrict__ out, int N) {
    int tid = threadIdx.x;
    int node = blockIdx.x * 8 + (tid >> 5);
    int q = tid & 31;
    if (node >= N) return;
    int beg = offs[node], end = offs[node + 1];
    float ax = 0, ay = 0, az = 0, aw = 0;
    float bx = 0, by = 0, bz = 0, bw = 0;
    int i = beg;
    for (; i + 1 < end; i += 2) {
        f16x4 v0 = *(const f16x4*)&g16[(long long)perm[i] * 128 + q * 4];
        f16x4 v1 = *(const f16x4*)&g16[(long long)perm[i + 1] * 128 + q * 4];
        ax += (float)v0[0]; ay += (float)v0[1]; az += (float)v0[2]; aw += (float)v0[3];
        bx += (float)v1[0]; by += (float)v1[1]; bz += (float)v1[2]; bw += (float)v1[3];
    }
    if (i < end) {
        f16x4 v0 = *(const f16x4*)&g16[(long long)perm[i] * 128 + q * 4];
        ax += (float)v0[0]; ay += (float)v0[1]; az += (float)v0[2]; aw += (float)v0[3];
    }
    float rc = 1.0f / fmaxf((float)(end - beg), 1.0f);
    f16x4 rv = *(const f16x4*)&r2h[(long long)node * 128 + q * 4];
    float4 bv = ((const float4*)b2l)[q];
    float4 o;
    o.x = (ax + bx) * rc + (float)rv[0] + bv.x;
    o.y = (ay + by) * rc + (float)rv[1] + bv.y;
    o.z = (az + bz) * rc + (float)rv[2] + bv.z;
    o.w = (aw + bw) * rc + (float)rv[3] + bv.w;
    ((float4*)out)[(long long)node * 32 + q] = o;
}

// ---------------- async global->LDS, 16B/lane ----------------
__device__ inline void gload16(const void* g, void* l) {
    __builtin_amdgcn_global_load_lds(
        (const __attribute__((address_space(1))) unsigned int*)g,
        (__attribute__((address_space(3))) unsigned int*)l,
        16, 0, 0);
}

// ================= fp16 MFMA GEMM, 256x256 tile, 16 waves, BK=128, 2 STAGES ==========
// C = A @ B^T in fp16 (fp32 accumulate). 391 blocks, 1024 threads = 16 waves
// (4x4 wave grid, 64x64 per wave, acc[4][4] = 64 VGPR, spill-free).
// K=256 in TWO stages of BK=128 (the stage-count lever: r14 8st=134us,
// r17/r20 4st=62-65us -> predicted 2st ~40us). LDS = A 64 KiB + B 64 KiB
// = 128 KiB (fits 160) -> 1 block/CU.
// Row stage-slice = 128 f16 = 256 B = 16 chunks of 16 B. Swizzle: chunk c of
// row r at slot c^(r&15); slots s/s+8 alias banks = 2-way only (free).
// DMA: 4 rows/issue (lane r4=lane>>4, slot scs=lane&15, src chunk
// scs^(row&15)); 8 issues/wave/stage (4 A + 4 B).
// LAYER 1: stage 0 = (m16, W1l), stage 1 = (x16, W1r) -- each exactly 128
//   k-wide, no k-offset. Epilogue relu+bias -> h f16 (stride 256) via OH.
// LAYER 2: A = h16 (stride 256, koff = kt*128); B row<128 -> W2l else W2r;
//   outputs g f16 (OH, cols 0..127) | r2 f16 (O1h, cols 128..255).
template <int LAYER>
__global__ __launch_bounds__(1024, 4) void gemm_mfma_k(
        const _Float16* __restrict__ Ap0, const _Float16* __restrict__ Ap1,
        const _Float16* __restrict__ Bp0, const _Float16* __restrict__ Bp1,
        const float* __restrict__ bias,
        _Float16* __restrict__ O1h,
        _Float16* __restrict__ OH, int N) {
    __shared__ _Float16 As[256 * 128];   // 64 KiB
    __shared__ _Float16 Bs[256 * 128];   // 64 KiB

    const int m0 = blockIdx.x * 256;
    const int tid = threadIdx.x;
    const int lane = tid & 63;
    const int wid = tid >> 6;           // 0..15
    const int wm = wid >> 2, wn = wid & 3;
    const int lr = lane & 15, lg = lane >> 4;

    // DMA lane geometry: 4 rows x 16 slots x 16 B = 1 KB per issue
    const int r4 = lane >> 4;          // row within 4-row segment
    const int scs = lane & 15;         // LDS slot this lane fills

    f32x4 acc[4][4];
#pragma unroll
    for (int i = 0; i < 4; i++)
#pragma unroll
        for (int j = 0; j < 4; j++) acc[i][j] = (f32x4)0.0f;

#pragma unroll
    for (int kt = 0; kt < 2; ++kt) {
        __syncthreads();    // previous stage's readers done
        // ---- STAGE kt: A 64 segs (4/wave), B 64 segs (4/wave) ----
        {
            const _Float16* Asrc;
            int aoffk;
            if constexpr (LAYER == 1) { Asrc = kt ? Ap1 : Ap0; aoffk = 0; }
            else                      { Asrc = Ap0;            aoffk = kt * 128; }
            constexpr int RSA = (LAYER == 1) ? 128 : 256;
#pragma unroll
            for (int it = 0; it < 4; ++it) {
                int seg = wid * 4 + it;          // 0..63
                int row = seg * 4 + r4;          // 0..255
                int k16 = scs ^ (row & 15);      // pre-swizzled source chunk
                int gn = m0 + row;
                if (gn < N)
                    gload16(Asrc + (long long)gn * RSA + aoffk + k16 * 8, &As[seg * 512]);
            }
#pragma unroll
            for (int it = 0; it < 4; ++it) {
                int seg = wid * 4 + it;          // 0..63
                int row = seg * 4 + r4;          // 0..255 (output col)
                int k16 = scs ^ (row & 15);
                const _Float16* Bsrc;
                long long boff;
                if constexpr (LAYER == 1) {
                    Bsrc = kt ? Bp1 : Bp0;                   // W1l / W1r, rows 0..255
                    boff = (long long)row * 128;
                } else {
                    Bsrc = (row < 128) ? Bp0 : Bp1;          // W2l / W2r
                    boff = (long long)(row & 127) * 256 + kt * 128;
                }
                gload16(Bsrc + boff + k16 * 8, &Bs[seg * 512]);
            }
        }
        __syncthreads();    // drain DMA: stage kt ready

        // ---- COMPUTE: 4 k-steps of 32 ----
#pragma unroll
        for (int ks = 0; ks < 4; ++ks) {
            const int c = ks * 4 + lg;           // k-chunk 0..15
            f16x8 bf[4];
#pragma unroll
            for (int fc = 0; fc < 4; ++fc) {
                int c_ = wn * 64 + fc * 16 + lr;             // 0..255
                bf[fc] = *(const f16x8*)&Bs[c_ * 128 + (c ^ (c_ & 15)) * 8];
            }
#pragma unroll
            for (int fr = 0; fr < 4; ++fr) {
                int r_ = wm * 64 + fr * 16 + lr;             // 0..255
                f16x8 af = *(const f16x8*)&As[r_ * 128 + (c ^ (r_ & 15)) * 8];
#pragma unroll
                for (int fc = 0; fc < 4; ++fc)
                    acc[fr][fc] = __builtin_amdgcn_mfma_f32_16x16x32_f16(af, bf[fc], acc[fr][fc], 0, 0, 0);
            }
        }
    }

    // ---- epilogue: C/D map col=lane&15, row=(lane>>4)*4+reg ----
    if constexpr (LAYER == 1) {
#pragma unroll
        for (int fc = 0; fc < 4; ++fc) {
            int col = wn * 64 + fc * 16 + lr;       // 0..255
            float bv = bias[col];
#pragma unroll
            for (int fr = 0; fr < 4; ++fr) {
#pragma unroll
                for (int j = 0; j < 4; ++j) {
                    int row = m0 + wm * 64 + fr * 16 + lg * 4 + j;
                    if (row < N)
                        OH[(long long)row * 256 + col] =
                            (_Float16)fmaxf(acc[fr][fc][j] + bv, 0.0f);
                }
            }
        }
    } else {
#pragma unroll
        for (int fc = 0; fc < 4; ++fc) {
            int col = wn * 64 + fc * 16 + lr;       // 0..255
            _Float16* dp = (col < 128) ? OH : O1h;  // g | r2 (uniform per wn)
            int dcol = col & 127;
#pragma unroll
            for (int fr = 0; fr < 4; ++fr) {
#pragma unroll
                for (int j = 0; j < 4; ++j) {
                    int row = m0 + wm * 64 + fr * 16 + lg * 4 + j;
                    if (row < N)
                        dp[(long long)row * 128 + dcol] = (_Float16)acc[fr][fc][j];
                }
            }
        }
    }
}

extern "C" void kernel_launch(void* const* d_in, const int* in_sizes, int n_in,
                              void* d_out, int out_size, void* d_ws, size_t ws_size,
                              hipStream_t stream) {
    const float* x   = (const float*)d_in[0];
    const int*   ei  = (const int*)d_in[1];     // [2, E]
    const float* W1l = (const float*)d_in[2];
    const float* b1l = (const float*)d_in[3];
    const float* W1r = (const float*)d_in[4];
    const float* W2l = (const float*)d_in[5];
    const float* b2l = (const float*)d_in[6];
    const float* W2r = (const float*)d_in[7];
    float* out = (float*)d_out;

    const int N = N_NODES, E = N_EDGES;
    const int* srcI = ei;
    const int* dstI = ei + E;

    char* ws = (char*)d_ws;
    size_t off = 0;
    auto alloc = [&](size_t bytes) {
        size_t o = off;
        off += (bytes + 511) & ~(size_t)511;
        return o;
    };
    size_t off_cnt   = alloc((size_t)N * 4);
    size_t off_offs  = alloc((size_t)(N + 1) * 4);
    size_t off_cur   = alloc((size_t)N * 4);
    size_t off_bsum  = alloc((size_t)SCAN_NB * 4);
    size_t off_boff  = alloc((size_t)SCAN_NB * 4);
    size_t off_perm  = alloc((size_t)E * 4);
    size_t off_x16   = alloc((size_t)N * 128 * 2);     // x f16
    size_t off_m16   = alloc((size_t)N * 128 * 2);     // mean f16
    size_t off_h16   = alloc((size_t)N * 256 * 2);     // h f16
    size_t off_g16   = alloc((size_t)N * 128 * 2);     // g f16
    size_t off_r2    = alloc((size_t)N * 128 * 2);     // r2 f16
    size_t off_w     = alloc((size_t)4 * 32768 * 2);   // 4 f16 weights
    int*      cntI = (int*)(ws + off_cnt);
    int*      offs = (int*)(ws + off_offs);
    int*      cur  = (int*)(ws + off_cur);
    int*      bsum = (int*)(ws + off_bsum);
    int*      boff = (int*)(ws + off_boff);
    int*      perm = (int*)(ws + off_perm);
    _Float16* x16  = (_Float16*)(ws + off_x16);
    _Float16* m16  = (_Float16*)(ws + off_m16);
    _Float16* h16  = (_Float16*)(ws + off_h16);
    _Float16* g16  = (_Float16*)(ws + off_g16);
    _Float16* r2h  = (_Float16*)(ws + off_r2);
    _Float16* wbuf = (_Float16*)(ws + off_w);
    const int WSZ = 32768;                             // 256*128 elems
    _Float16* w1l16 = wbuf;            _Float16* w1r16 = wbuf + WSZ;
    _Float16* w2l16 = wbuf + 2 * WSZ;  _Float16* w2r16 = wbuf + 3 * WSZ;

    // ---- CSR build ----
    (void)hipMemsetAsync(cntI, 0, (size_t)N * 4, stream);
    count_int_k<<<(E + 255) / 256, 256, 0, stream>>>(dstI, cntI, E);
    scan1_k<<<SCAN_NB, 256, 0, stream>>>(cntI, offs, bsum, N);
    scan2_k<<<1, 256, 0, stream>>>(bsum, boff, SCAN_NB);
    scan3_k<<<(N + 255) / 256, 256, 0, stream>>>(offs, cur, boff, N, E);
    fill_k<<<(E + 255) / 256, 256, 0, stream>>>(srcI, dstI, cur, perm, E);

    // ---- f16 conversions ----
    {
        int n8x = N * 16;                          // N*128/8
        cvt_f16_k<<<(n8x + 255) / 256, 256, 0, stream>>>(x, x16, n8x);
        int n8w = 32768 / 8;                       // 4096
        cvt_f16_k<<<(n8w + 255) / 256, 256, 0, stream>>>(W1l, w1l16, n8w);
        cvt_f16_k<<<(n8w + 255) / 256, 256, 0, stream>>>(W1r, w1r16, n8w);
        cvt_f16_k<<<(n8w + 255) / 256, 256, 0, stream>>>(W2l, w2l16, n8w);
        cvt_f16_k<<<(n8w + 255) / 256, 256, 0, stream>>>(W2r, w2r16, n8w);
    }

    // ---- layer 1 ----
    aggmean_k<<<(N + 7) / 8, 256, 0, stream>>>(x16, perm, offs, m16, N);
    {
        int nblk = (N + 255) / 256;   // 391
        gemm_mfma_k<1><<<nblk, 1024, 0, stream>>>(m16, x16, w1l16, w1r16,
                                                  b1l, nullptr, h16, N);
    }

    // ---- layer 2 ----
    {
        int nblk = (N + 255) / 256;
        gemm_mfma_k<2><<<nblk, 1024, 0, stream>>>(h16, h16, w2l16, w2r16,
                                                  nullptr, r2h, g16, N);
    }
    aggout_k<<<(N + 7) / 8, 256, 0, stream>>>(g16, perm, offs, r2h, b2l, out, N);
}